// Round 12
// baseline (591.711 us; speedup 1.0000x reference)
//
#include <hip/hip_runtime.h>
#include <hip/hip_fp16.h>
#include <math.h>

// Decomposition:
//   h = mlp_self(feat); A = h @ Wnm[0:128]; a_s = A@m; bd[v] = feat[v]@qb
//   w_e = exp(lrelu(a_s[src] + c1*bit + bd[dst] + c0, 0.2))  (no max; fp32-safe)
//   neigh[v] = (sum w_e*A[src] + (sum w_e*bit)*wbit)/sum_w + B[v] + b_nm
//   out = mlp_out(relu(neigh))
// R1: same-address atomicAdd serializes -> block reduce.
// R6: A stored fp16 (|A|<50; 4.9e-4 passes).
// R7/R8: CSR fill floor = 1 random dirty line/edge; flat fill (100k cursors) wins.
// R9/R10/R11 chronic issue: compiler NEVER keeps the per-thread weight array
//     resident (VGPR=84/72/52) -> reloads all weights from L2 per block; with
//     grid=ntile each block does ONE tile so setup ~= work.
// R12: (a) asm volatile register pin on the weight array -> rematerialization
//     impossible; (b) grid=960 + grid-stride so the one-time weight load
//     amortizes over ~6.5 tiles/block. fp16 rows + v_dot2_f32_f16 kept.

typedef _Float16 h2f __attribute__((ext_vector_type(2)));

static __device__ __forceinline__ float lrelu(float x, float s) {
    return x >= 0.f ? x : s * x;
}
static __device__ __forceinline__ float fdot2(h2f a, h2f b, float c) {
    return __builtin_amdgcn_fdot2(a, b, c, false);
}

__global__ void k_init(int* counts, int n) {
    int i = blockIdx.x * blockDim.x + threadIdx.x;
    if (i < n) counts[i] = 0;
}

__global__ void k_hist(const int* dst, int* counts, int E) {
    int e = blockIdx.x * blockDim.x + threadIdx.x;
    if (e < E) atomicAdd(&counts[dst[e]], 1);
}

__global__ void k_scan_a(const int* counts, int* row_off, int* partials, int n) {
    __shared__ int sd[256];
    int t = threadIdx.x;
    int base = blockIdx.x * 1024 + t * 4;
    int v0 = (base + 0 < n) ? counts[base + 0] : 0;
    int v1 = (base + 1 < n) ? counts[base + 1] : 0;
    int v2 = (base + 2 < n) ? counts[base + 2] : 0;
    int v3 = (base + 3 < n) ? counts[base + 3] : 0;
    int s = v0 + v1 + v2 + v3;
    sd[t] = s; __syncthreads();
    for (int off = 1; off < 256; off <<= 1) {
        int x = (t >= off) ? sd[t - off] : 0;
        __syncthreads();
        sd[t] += x;
        __syncthreads();
    }
    int run = sd[t] - s;
    if (base + 0 < n) row_off[base + 0] = run; run += v0;
    if (base + 1 < n) row_off[base + 1] = run; run += v1;
    if (base + 2 < n) row_off[base + 2] = run; run += v2;
    if (base + 3 < n) row_off[base + 3] = run;
    if (t == 255) partials[blockIdx.x] = sd[255];
}
__global__ void k_scan_b(int* partials, int nb) {
    if (threadIdx.x == 0 && blockIdx.x == 0) {
        int acc = 0;
        for (int i = 0; i < nb; i++) { int x = partials[i]; partials[i] = acc; acc += x; }
    }
}
__global__ void k_scan_c(int* row_off, const int* partials, int* cursor, int n, int E) {
    int i = blockIdx.x * blockDim.x + threadIdx.x;
    if (i < n) {
        int r = row_off[i] + partials[i >> 10];
        row_off[i] = r;
        cursor[i] = r;
    }
    if (i == 0) row_off[n] = E;
}

// sc[0]=c1=wbit@m  sc[1]=c0=b_nm@m  sc[2+k]=qb[k]=Wnm[129+k]@m
__global__ void k_scalars(const float* Wnm, const float* b_nm, const float* attn, float* sc) {
    __shared__ float red[128];
    int t = threadIdx.x;
    float m = attn[t];
    red[t] = Wnm[128 * 128 + t] * m; __syncthreads();
    for (int s = 64; s > 0; s >>= 1) { if (t < s) red[t] += red[t + s]; __syncthreads(); }
    if (t == 0) sc[0] = red[0];
    __syncthreads();
    red[t] = b_nm[t] * m; __syncthreads();
    for (int s = 64; s > 0; s >>= 1) { if (t < s) red[t] += red[t + s]; __syncthreads(); }
    if (t == 0) sc[1] = red[0];
    __syncthreads();
    for (int k = 0; k < 16; k++) {
        red[t] = Wnm[(129 + k) * 128 + t] * m; __syncthreads();
        for (int s = 64; s > 0; s >>= 1) { if (t < s) red[t] += red[t + s]; __syncthreads(); }
        if (t == 0) sc[2 + k] = red[0];
        __syncthreads();
    }
}

// bd[v] = feat[v] @ qb
__global__ void k_bd(const float* __restrict__ feat, const float* __restrict__ sc,
                     float* __restrict__ bd, int n) {
    int i = blockIdx.x * blockDim.x + threadIdx.x;
    if (i >= n) return;
    const float4* fr = (const float4*)(feat + (size_t)i * 16);
    float acc = 0.f;
#pragma unroll
    for (int q = 0; q < 4; q++) {
        float4 f = fr[q];
        acc = fmaf(f.x, sc[2 + 4 * q + 0], acc);
        acc = fmaf(f.y, sc[2 + 4 * q + 1], acc);
        acc = fmaf(f.z, sc[2 + 4 * q + 2], acc);
        acc = fmaf(f.w, sc[2 + 4 * q + 3], acc);
    }
    bd[i] = acc;
}

// ---------- t1 = lrelu(feat@W1 + b1, 0.1)   [N,64] fp32 ----------
__global__ void __launch_bounds__(256, 4) k_t1(const float* __restrict__ feat,
                                               const float* __restrict__ W1,
                                               const float* __restrict__ b1,
                                               float* __restrict__ t1, int n) {
    int col = threadIdx.x & 63;
    int rg  = threadIdx.x >> 6;
    float w[16];
#pragma unroll
    for (int k = 0; k < 16; k++) w[k] = W1[k * 64 + col];
    float b = b1[col];
    for (int i = blockIdx.x * 4 + rg; i < n; i += gridDim.x * 4) {
        const float4* fr = (const float4*)(feat + (size_t)i * 16);
        float4 f0 = fr[0], f1 = fr[1], f2 = fr[2], f3 = fr[3];
        float acc = b;
        acc = fmaf(f0.x, w[0], acc);  acc = fmaf(f0.y, w[1], acc);
        acc = fmaf(f0.z, w[2], acc);  acc = fmaf(f0.w, w[3], acc);
        acc = fmaf(f1.x, w[4], acc);  acc = fmaf(f1.y, w[5], acc);
        acc = fmaf(f1.z, w[6], acc);  acc = fmaf(f1.w, w[7], acc);
        acc = fmaf(f2.x, w[8], acc);  acc = fmaf(f2.y, w[9], acc);
        acc = fmaf(f2.z, w[10], acc); acc = fmaf(f2.w, w[11], acc);
        acc = fmaf(f3.x, w[12], acc); acc = fmaf(f3.y, w[13], acc);
        acc = fmaf(f3.z, w[14], acc); acc = fmaf(f3.w, w[15], acc);
        t1[(size_t)i * 64 + col] = lrelu(acc, 0.1f);
    }
}

// ---------- h(fp16) = t1@W2 + b2   [N,128], LDS tile, pinned fp32 weights ----------
__global__ void __launch_bounds__(128, 1) k_h(const float* __restrict__ t1,
                                              const float* __restrict__ W2,
                                              const float* __restrict__ b2,
                                              __half* __restrict__ hH, int nt) {
    int t = threadIdx.x;
    float w[64];
#pragma unroll
    for (int j = 0; j < 64; j++) w[j] = W2[j * 128 + t];
#pragma unroll
    for (int j = 0; j < 64; j++) asm volatile("" : "+v"(w[j]));   // pin: no remat
    float b = b2[t];
    __shared__ __align__(16) float ts[16 * 64];
    for (int base = blockIdx.x * 16; base < nt; base += gridDim.x * 16) {
        int rows = min(16, nt - base);
        const float4* gsrc = (const float4*)(t1 + (size_t)base * 64);
        for (int j = t; j < rows * 16; j += 128) ((float4*)ts)[j] = gsrc[j];
        __syncthreads();
        for (int r = 0; r < rows; ++r) {
            const float4* tr = (const float4*)(ts + r * 64);
            float acc = b;
#pragma unroll
            for (int j4 = 0; j4 < 16; j4++) {
                float4 tv = tr[j4];
                acc = fmaf(tv.x, w[4 * j4 + 0], acc);
                acc = fmaf(tv.y, w[4 * j4 + 1], acc);
                acc = fmaf(tv.z, w[4 * j4 + 2], acc);
                acc = fmaf(tv.w, w[4 * j4 + 3], acc);
            }
            hH[(size_t)(base + r) * 128 + t] = __float2half_rn(acc);
        }
        __syncthreads();
    }
}

// ---------- A(fp16) = h(fp16)@Wnm_top ; a_s = A@m ; dot2, pinned half2 weights ----------
__global__ void __launch_bounds__(128, 1) k_A(const __half* __restrict__ hH,
                                              const float* __restrict__ Wnm,
                                              const float* __restrict__ attn,
                                              __half* __restrict__ Ah,
                                              float* __restrict__ a_s, int n) {
    int t = threadIdx.x;
    h2f w2[64];
#pragma unroll
    for (int j2 = 0; j2 < 64; j2++) {
        h2f p; p[0] = (_Float16)Wnm[(2 * j2) * 128 + t];
        p[1] = (_Float16)Wnm[(2 * j2 + 1) * 128 + t];
        w2[j2] = p;
    }
#pragma unroll
    for (int j2 = 0; j2 < 64; j2++) asm volatile("" : "+v"(w2[j2]));   // pin
    float mc = attn[t];
    __shared__ __align__(16) __half hs[16 * 128];
    __shared__ float crossb[32];
    for (int base = blockIdx.x * 16; base < n; base += gridDim.x * 16) {
        int rows = min(16, n - base);
        const float4* gsrc = (const float4*)(hH + (size_t)base * 128);
        for (int j = t; j < rows * 16; j += 128) ((float4*)hs)[j] = gsrc[j];
        __syncthreads();
        for (int r = 0; r < rows; ++r) {
            const float4* hr = (const float4*)(hs + r * 128);
            float a0 = 0.f, a1 = 0.f, a2 = 0.f, a3 = 0.f;
#pragma unroll
            for (int j4 = 0; j4 < 16; j4++) {
                float4 q = hr[j4];
                const h2f* hh = (const h2f*)&q;
                a0 = fdot2(hh[0], w2[4 * j4 + 0], a0);
                a1 = fdot2(hh[1], w2[4 * j4 + 1], a1);
                a2 = fdot2(hh[2], w2[4 * j4 + 2], a2);
                a3 = fdot2(hh[3], w2[4 * j4 + 3], a3);
            }
            float acc = (a0 + a1) + (a2 + a3);
            Ah[(size_t)(base + r) * 128 + t] = __float2half_rn(acc);
            float red = acc * mc;
#pragma unroll
            for (int o = 32; o > 0; o >>= 1) red += __shfl_down(red, o, 64);
            if ((t & 63) == 0) crossb[r * 2 + (t >> 6)] = red;
        }
        __syncthreads();
        if (t < rows) a_s[base + t] = crossb[t * 2] + crossb[t * 2 + 1];
        __syncthreads();
    }
}

// ---------- fill CSR: one 16B record {src, w, w*bit, pad} per edge ----------
__global__ void k_fill(const int* __restrict__ src, const int* __restrict__ dst,
                       const float* __restrict__ bit, int* __restrict__ cursor,
                       const float* __restrict__ a_s, const float* __restrict__ bd,
                       const float* __restrict__ sc, float4* __restrict__ recs, int E) {
    int e = blockIdx.x * blockDim.x + threadIdx.x;
    if (e >= E) return;
    int s = src[e], d = dst[e];
    float bv = bit[e];
    float logit = a_s[s] + sc[0] * bv + bd[d] + sc[1];
    float w = __expf(lrelu(logit, 0.2f));
    int p = atomicAdd(&cursor[d], 1);
    recs[p] = make_float4(__int_as_float(s), w, w * bv, 0.f);
}

// ---------- per-node aggregate -> h_node fp16; 64 thr, 2 ch/thread ----------
__global__ void __launch_bounds__(64, 4) k_node(const float* __restrict__ feat,
                                                const float* __restrict__ Wnm,
                                                const float* __restrict__ b_nm,
                                                const __half* __restrict__ Ah,
                                                const int* __restrict__ row_off,
                                                const float4* __restrict__ recs,
                                                __half* __restrict__ h_node) {
    int v = blockIdx.x;
    int t = threadIdx.x;
    int rs = row_off[v], re = row_off[v + 1];
    h2f* outp = (h2f*)&h_node[(size_t)v * 128 + 2 * t];
    const float4* fr = (const float4*)(feat + (size_t)v * 16);
    float fv[16];
    *(float4*)&fv[0]  = fr[0];
    *(float4*)&fv[4]  = fr[1];
    *(float4*)&fv[8]  = fr[2];
    *(float4*)&fv[12] = fr[3];
    float Bx = 0.f, By = 0.f;
#pragma unroll
    for (int k = 0; k < 16; k++) {
        float2 wr = *(const float2*)&Wnm[(129 + k) * 128 + 2 * t];
        Bx = fmaf(fv[k], wr.x, Bx);
        By = fmaf(fv[k], wr.y, By);
    }
    if (re == rs) { h2f z; z[0] = (_Float16)0.f; z[1] = (_Float16)0.f; *outp = z; return; }
    float ax = 0.f, ay = 0.f, sw = 0.f, swb = 0.f;
#pragma unroll 4
    for (int p = rs; p < re; ++p) {
        float4 rec = recs[p];
        int sv = __float_as_int(rec.x);
        float2 av = __half22float2(*(const __half2*)&Ah[(size_t)sv * 128 + 2 * t]);
        ax = fmaf(rec.y, av.x, ax);
        ay = fmaf(rec.y, av.y, ay);
        sw += rec.y;
        swb += rec.z;
    }
    float inv = 1.f / sw;
    float2 wb = *(const float2*)&Wnm[128 * 128 + 2 * t];
    float2 bn = *(const float2*)&b_nm[2 * t];
    float hx = fmaf(swb * inv, wb.x, ax * inv) + Bx + bn.x;
    float hy = fmaf(swb * inv, wb.y, ay * inv) + By + bn.y;
    h2f o; o[0] = (_Float16)fmaxf(hx, 0.f); o[1] = (_Float16)fmaxf(hy, 0.f);
    *outp = o;
}

// ---------- out = bo2 + sum_c lrelu(h_node@Wo1+bo1,0.1)[c]*Wo2[c]; pinned ----------
__global__ void __launch_bounds__(128, 1) k_out(const __half* __restrict__ h_node,
                                                const float* __restrict__ Wo1,
                                                const float* __restrict__ bo1,
                                                const float* __restrict__ Wo2,
                                                const float* __restrict__ bo2,
                                                float* __restrict__ out, int n) {
    int t = threadIdx.x;
    h2f wp[64];
#pragma unroll
    for (int j2 = 0; j2 < 64; j2++) {
        h2f p; p[0] = (_Float16)Wo1[(2 * j2) * 128 + t];
        p[1] = (_Float16)Wo1[(2 * j2 + 1) * 128 + t];
        wp[j2] = p;
    }
#pragma unroll
    for (int j2 = 0; j2 < 64; j2++) asm volatile("" : "+v"(wp[j2]));   // pin
    float b  = bo1[t];
    float wo2 = Wo2[t];
    float bias2 = bo2[0];
    __shared__ __align__(16) __half hs[16 * 128];
    __shared__ float crossb[32];
    for (int base = blockIdx.x * 16; base < n; base += gridDim.x * 16) {
        int rows = min(16, n - base);
        const float4* gsrc = (const float4*)(h_node + (size_t)base * 128);
        for (int j = t; j < rows * 16; j += 128) ((float4*)hs)[j] = gsrc[j];
        __syncthreads();
        for (int r = 0; r < rows; ++r) {
            const float4* hr = (const float4*)(hs + r * 128);
            float a0 = 0.f, a1 = 0.f, a2 = 0.f, a3 = 0.f;
#pragma unroll
            for (int j4 = 0; j4 < 16; j4++) {
                float4 q = hr[j4];
                const h2f* hh = (const h2f*)&q;
                a0 = fdot2(hh[0], wp[4 * j4 + 0], a0);
                a1 = fdot2(hh[1], wp[4 * j4 + 1], a1);
                a2 = fdot2(hh[2], wp[4 * j4 + 2], a2);
                a3 = fdot2(hh[3], wp[4 * j4 + 3], a3);
            }
            float red = lrelu(((a0 + a1) + (a2 + a3)) + b, 0.1f) * wo2;
#pragma unroll
            for (int o = 32; o > 0; o >>= 1) red += __shfl_down(red, o, 64);
            if ((t & 63) == 0) crossb[r * 2 + (t >> 6)] = red;
        }
        __syncthreads();
        if (t < rows) out[base + t] = bias2 + crossb[t * 2] + crossb[t * 2 + 1];
        __syncthreads();
    }
}

extern "C" void kernel_launch(void* const* d_in, const int* in_sizes, int n_in,
                              void* d_out, int out_size, void* d_ws, size_t ws_size,
                              hipStream_t stream) {
    const float* feat = (const float*)d_in[0];
    const float* bit  = (const float*)d_in[1];
    const int*   src  = (const int*)d_in[2];
    const int*   dst  = (const int*)d_in[3];
    const float* W1   = (const float*)d_in[4];
    const float* b1   = (const float*)d_in[5];
    const float* W2   = (const float*)d_in[6];
    const float* b2   = (const float*)d_in[7];
    const float* Wnm  = (const float*)d_in[8];
    const float* bnm  = (const float*)d_in[9];
    const float* attn = (const float*)d_in[10];
    const float* Wo1  = (const float*)d_in[11];
    const float* bo1  = (const float*)d_in[12];
    const float* Wo2  = (const float*)d_in[13];
    const float* bo2  = (const float*)d_in[14];
    float* out = (float*)d_out;
    int n = in_sizes[0] / 16;
    int E = in_sizes[2];

    char* wsp = (char*)d_ws;
    size_t off = 0;
    auto alloc = [&](size_t bytes) -> void* {
        void* p = wsp + off;
        off = (off + bytes + 255) & ~(size_t)255;
        return p;
    };
    __half* Ah       = (__half*)alloc((size_t)n * 128 * 2);
    __half* hH       = (__half*)alloc((size_t)n * 128 * 2);   // h, then h_node
    float*  t1       = (float*)alloc((size_t)n * 64 * 4);
    float*  a_s      = (float*)alloc((size_t)n * 4);
    float*  bd       = (float*)alloc((size_t)n * 4);
    int*    counts   = (int*)alloc((size_t)n * 4);
    int*    row_off  = (int*)alloc((size_t)(n + 1) * 4);
    int*    cursor   = (int*)alloc((size_t)n * 4);
    int*    partials = (int*)alloc(8192);
    float*  sc       = (float*)alloc(256);
    float4* recs     = (float4*)alloc((size_t)E * 16);

    int nb256 = (n + 255) / 256;
    int eb256 = (E + 255) / 256;
    int nscan = (n + 1023) / 1024;

    k_init<<<nb256, 256, 0, stream>>>(counts, n);
    k_hist<<<eb256, 256, 0, stream>>>(dst, counts, E);
    k_scan_a<<<nscan, 256, 0, stream>>>(counts, row_off, partials, n);
    k_scan_b<<<1, 64, 0, stream>>>(partials, nscan);
    k_scan_c<<<nb256, 256, 0, stream>>>(row_off, partials, cursor, n, E);
    k_scalars<<<1, 128, 0, stream>>>(Wnm, bnm, attn, sc);
    k_bd<<<nb256, 256, 0, stream>>>(feat, sc, bd, n);
    k_t1<<<2048, 256, 0, stream>>>(feat, W1, b1, t1, n);
    k_h<<<960, 128, 0, stream>>>(t1, W2, b2, hH, n);
    k_A<<<960, 128, 0, stream>>>(hH, Wnm, attn, Ah, a_s, n);
    k_fill<<<eb256, 256, 0, stream>>>(src, dst, bit, cursor, a_s, bd, sc, recs, E);
    k_node<<<n, 64, 0, stream>>>(feat, Wnm, bnm, Ah, row_off, recs, hH);
    k_out<<<960, 128, 0, stream>>>(hH, Wo1, bo1, Wo2, bo2, out, n);
}

// Round 13
// 414.824 us; speedup vs baseline: 1.4264x; 1.4264x over previous
//
#include <hip/hip_runtime.h>
#include <hip/hip_fp16.h>
#include <math.h>

// Decomposition:
//   h = mlp_self(feat); A = h @ Wnm[0:128]; a_s = A@m; bd[v] = feat[v]@qb
//   w_e = exp(lrelu(a_s[src] + c1*bit + bd[dst] + c0, 0.2))  (no max; fp32-safe)
//   neigh[v] = (sum w_e*A[src] + (sum w_e*bit)*wbit)/sum_w + B[v] + b_nm
//   out = mlp_out(relu(neigh))
// R1: same-address atomicAdd serializes -> block reduce.
// R6: fp16 A gather (halves k_node bytes).
// R7/R8: CSR fill floor = 1 random dirty 64B line/edge (~130us); flat fill wins.
// R9-R12 chronic: per-lane-column matvecs are LDS-broadcast-issue-bound
//     (every lane reads every row element; ~384cyc/row/CU) and the compiler
//     never keeps weight arrays in VGPRs (pin failed, VGPR stuck ~50).
// R13: MFMA (v_mfma_f32_16x16x32_f16) for k_h/k_A/k_out. W^T staged once per
//     block in LDS (stride 136/72 halves: 16B-aligned, 2-way-bank free);
//     4 waves/block grid-stride 16-row tiles, NO inner barriers; A-frags
//     direct from global. Layouts: A[m=lane&15][k=quad*8+j] (m120-verified),
//     C/D col=lane&15,row=quad*4+reg (m89-verified, dtype-independent).

typedef _Float16 h2f __attribute__((ext_vector_type(2)));
typedef _Float16 h8  __attribute__((ext_vector_type(8)));
typedef float    f4  __attribute__((ext_vector_type(4)));

static __device__ __forceinline__ float lrelu(float x, float s) {
    return x >= 0.f ? x : s * x;
}

__global__ void k_init(int* counts, int n) {
    int i = blockIdx.x * blockDim.x + threadIdx.x;
    if (i < n) counts[i] = 0;
}

__global__ void k_hist(const int* dst, int* counts, int E) {
    int e = blockIdx.x * blockDim.x + threadIdx.x;
    if (e < E) atomicAdd(&counts[dst[e]], 1);
}

__global__ void k_scan_a(const int* counts, int* row_off, int* partials, int n) {
    __shared__ int sd[256];
    int t = threadIdx.x;
    int base = blockIdx.x * 1024 + t * 4;
    int v0 = (base + 0 < n) ? counts[base + 0] : 0;
    int v1 = (base + 1 < n) ? counts[base + 1] : 0;
    int v2 = (base + 2 < n) ? counts[base + 2] : 0;
    int v3 = (base + 3 < n) ? counts[base + 3] : 0;
    int s = v0 + v1 + v2 + v3;
    sd[t] = s; __syncthreads();
    for (int off = 1; off < 256; off <<= 1) {
        int x = (t >= off) ? sd[t - off] : 0;
        __syncthreads();
        sd[t] += x;
        __syncthreads();
    }
    int run = sd[t] - s;
    if (base + 0 < n) row_off[base + 0] = run; run += v0;
    if (base + 1 < n) row_off[base + 1] = run; run += v1;
    if (base + 2 < n) row_off[base + 2] = run; run += v2;
    if (base + 3 < n) row_off[base + 3] = run;
    if (t == 255) partials[blockIdx.x] = sd[255];
}
__global__ void k_scan_b(int* partials, int nb) {
    if (threadIdx.x == 0 && blockIdx.x == 0) {
        int acc = 0;
        for (int i = 0; i < nb; i++) { int x = partials[i]; partials[i] = acc; acc += x; }
    }
}
__global__ void k_scan_c(int* row_off, const int* partials, int* cursor, int n, int E) {
    int i = blockIdx.x * blockDim.x + threadIdx.x;
    if (i < n) {
        int r = row_off[i] + partials[i >> 10];
        row_off[i] = r;
        cursor[i] = r;
    }
    if (i == 0) row_off[n] = E;
}

// sc[0]=c1=wbit@m  sc[1]=c0=b_nm@m  sc[2+k]=qb[k]=Wnm[129+k]@m
__global__ void k_scalars(const float* Wnm, const float* b_nm, const float* attn, float* sc) {
    __shared__ float red[128];
    int t = threadIdx.x;
    float m = attn[t];
    red[t] = Wnm[128 * 128 + t] * m; __syncthreads();
    for (int s = 64; s > 0; s >>= 1) { if (t < s) red[t] += red[t + s]; __syncthreads(); }
    if (t == 0) sc[0] = red[0];
    __syncthreads();
    red[t] = b_nm[t] * m; __syncthreads();
    for (int s = 64; s > 0; s >>= 1) { if (t < s) red[t] += red[t + s]; __syncthreads(); }
    if (t == 0) sc[1] = red[0];
    __syncthreads();
    for (int k = 0; k < 16; k++) {
        red[t] = Wnm[(129 + k) * 128 + t] * m; __syncthreads();
        for (int s = 64; s > 0; s >>= 1) { if (t < s) red[t] += red[t + s]; __syncthreads(); }
        if (t == 0) sc[2 + k] = red[0];
        __syncthreads();
    }
}

// bd[v] = feat[v] @ qb
__global__ void k_bd(const float* __restrict__ feat, const float* __restrict__ sc,
                     float* __restrict__ bd, int n) {
    int i = blockIdx.x * blockDim.x + threadIdx.x;
    if (i >= n) return;
    const float4* fr = (const float4*)(feat + (size_t)i * 16);
    float acc = 0.f;
#pragma unroll
    for (int q = 0; q < 4; q++) {
        float4 f = fr[q];
        acc = fmaf(f.x, sc[2 + 4 * q + 0], acc);
        acc = fmaf(f.y, sc[2 + 4 * q + 1], acc);
        acc = fmaf(f.z, sc[2 + 4 * q + 2], acc);
        acc = fmaf(f.w, sc[2 + 4 * q + 3], acc);
    }
    bd[i] = acc;
}

// ---------- t1(fp16) = lrelu(feat@W1 + b1, 0.1)   [N,64] ----------
__global__ void __launch_bounds__(256, 4) k_t1(const float* __restrict__ feat,
                                               const float* __restrict__ W1,
                                               const float* __restrict__ b1,
                                               __half* __restrict__ t1h, int n) {
    int col = threadIdx.x & 63;
    int rg  = threadIdx.x >> 6;
    float w[16];
#pragma unroll
    for (int k = 0; k < 16; k++) w[k] = W1[k * 64 + col];
    float b = b1[col];
    for (int i = blockIdx.x * 4 + rg; i < n; i += gridDim.x * 4) {
        const float4* fr = (const float4*)(feat + (size_t)i * 16);
        float4 f0 = fr[0], f1 = fr[1], f2 = fr[2], f3 = fr[3];
        float acc = b;
        acc = fmaf(f0.x, w[0], acc);  acc = fmaf(f0.y, w[1], acc);
        acc = fmaf(f0.z, w[2], acc);  acc = fmaf(f0.w, w[3], acc);
        acc = fmaf(f1.x, w[4], acc);  acc = fmaf(f1.y, w[5], acc);
        acc = fmaf(f1.z, w[6], acc);  acc = fmaf(f1.w, w[7], acc);
        acc = fmaf(f2.x, w[8], acc);  acc = fmaf(f2.y, w[9], acc);
        acc = fmaf(f2.z, w[10], acc); acc = fmaf(f2.w, w[11], acc);
        acc = fmaf(f3.x, w[12], acc); acc = fmaf(f3.y, w[13], acc);
        acc = fmaf(f3.z, w[14], acc); acc = fmaf(f3.w, w[15], acc);
        t1h[(size_t)i * 64 + col] = __float2half_rn(lrelu(acc, 0.1f));
    }
}

// ---------- h(fp16) = t1h @ W2 + b2   [N,64]@[64,128], MFMA ----------
__global__ void __launch_bounds__(256) k_h(const __half* __restrict__ t1h,
                                           const float* __restrict__ W2,
                                           const float* __restrict__ b2,
                                           __half* __restrict__ hH,
                                           int n, int ntiles) {
    __shared__ __half Wt[128 * 72];   // Wt[c][k], stride 72 (144B: 16B-aligned, 2-way banks)
    int t = threadIdx.x;
    for (int idx = t; idx < 64 * 128; idx += 256) {
        int k = idx >> 7, c = idx & 127;
        Wt[c * 72 + k] = __float2half_rn(W2[idx]);
    }
    __syncthreads();
    int wave = t >> 6, lane = t & 63;
    int c = lane & 15, q = lane >> 4;
    float bv[8];
#pragma unroll
    for (int ct = 0; ct < 8; ct++) bv[ct] = b2[ct * 16 + c];
    for (int tile = blockIdx.x * 4 + wave; tile < ntiles; tile += gridDim.x * 4) {
        int rowbase = tile * 16;
        int rm = min(rowbase + c, n - 1);
        h8 af[2];
#pragma unroll
        for (int ks = 0; ks < 2; ks++)
            af[ks] = *(const h8*)&t1h[(size_t)rm * 64 + ks * 32 + q * 8];
        f4 acc[8];
#pragma unroll
        for (int ct = 0; ct < 8; ct++) acc[ct] = (f4)(0.f);
#pragma unroll
        for (int ct = 0; ct < 8; ct++) {
#pragma unroll
            for (int ks = 0; ks < 2; ks++) {
                h8 bf = *(const h8*)&Wt[(ct * 16 + c) * 72 + ks * 32 + q * 8];
                acc[ct] = __builtin_amdgcn_mfma_f32_16x16x32_f16(af[ks], bf, acc[ct], 0, 0, 0);
            }
        }
        int rlim = n - rowbase;
#pragma unroll
        for (int ct = 0; ct < 8; ct++) {
            int col = ct * 16 + c;
#pragma unroll
            for (int reg = 0; reg < 4; reg++) {
                int rr = q * 4 + reg;
                if (rr < rlim)
                    hH[(size_t)(rowbase + rr) * 128 + col] = __float2half_rn(acc[ct][reg] + bv[ct]);
            }
        }
    }
}

// ---------- A(fp16) = hH @ Wnm_top ; a_s = A@m   [N,128]@[128,128], MFMA ----------
__global__ void __launch_bounds__(256) k_A(const __half* __restrict__ hH,
                                           const float* __restrict__ Wnm,
                                           const float* __restrict__ attn,
                                           __half* __restrict__ Ah,
                                           float* __restrict__ a_s,
                                           int n, int ntiles) {
    __shared__ __half Wt[128 * 136];  // Wt[c][k], stride 136 (272B: 16B-aligned, 2-way banks)
    int t = threadIdx.x;
    for (int idx = t; idx < 128 * 128; idx += 256) {
        int k = idx >> 7, c = idx & 127;
        Wt[c * 136 + k] = __float2half_rn(Wnm[idx]);
    }
    __syncthreads();
    int wave = t >> 6, lane = t & 63;
    int c = lane & 15, q = lane >> 4;
    float attv[8];
#pragma unroll
    for (int ct = 0; ct < 8; ct++) attv[ct] = attn[ct * 16 + c];
    for (int tile = blockIdx.x * 4 + wave; tile < ntiles; tile += gridDim.x * 4) {
        int rowbase = tile * 16;
        int rm = min(rowbase + c, n - 1);
        h8 af[4];
#pragma unroll
        for (int ks = 0; ks < 4; ks++)
            af[ks] = *(const h8*)&hH[(size_t)rm * 128 + ks * 32 + q * 8];
        f4 acc[8];
#pragma unroll
        for (int ct = 0; ct < 8; ct++) acc[ct] = (f4)(0.f);
#pragma unroll
        for (int ct = 0; ct < 8; ct++) {
#pragma unroll
            for (int ks = 0; ks < 4; ks++) {
                h8 bf = *(const h8*)&Wt[(ct * 16 + c) * 136 + ks * 32 + q * 8];
                acc[ct] = __builtin_amdgcn_mfma_f32_16x16x32_f16(af[ks], bf, acc[ct], 0, 0, 0);
            }
        }
        int rlim = n - rowbase;
        float s0 = 0.f, s1 = 0.f, s2 = 0.f, s3 = 0.f;
#pragma unroll
        for (int ct = 0; ct < 8; ct++) {
            int col = ct * 16 + c;
#pragma unroll
            for (int reg = 0; reg < 4; reg++) {
                int rr = q * 4 + reg;
                if (rr < rlim)
                    Ah[(size_t)(rowbase + rr) * 128 + col] = __float2half_rn(acc[ct][reg]);
            }
            s0 = fmaf(acc[ct][0], attv[ct], s0);
            s1 = fmaf(acc[ct][1], attv[ct], s1);
            s2 = fmaf(acc[ct][2], attv[ct], s2);
            s3 = fmaf(acc[ct][3], attv[ct], s3);
        }
#pragma unroll
        for (int off = 1; off < 16; off <<= 1) {
            s0 += __shfl_xor(s0, off, 64);
            s1 += __shfl_xor(s1, off, 64);
            s2 += __shfl_xor(s2, off, 64);
            s3 += __shfl_xor(s3, off, 64);
        }
        if (c == 0) {
            if (q * 4 + 0 < rlim) a_s[rowbase + q * 4 + 0] = s0;
            if (q * 4 + 1 < rlim) a_s[rowbase + q * 4 + 1] = s1;
            if (q * 4 + 2 < rlim) a_s[rowbase + q * 4 + 2] = s2;
            if (q * 4 + 3 < rlim) a_s[rowbase + q * 4 + 3] = s3;
        }
    }
}

// ---------- fill CSR: one 16B record {src, w, w*bit, pad} per edge ----------
__global__ void k_fill(const int* __restrict__ src, const int* __restrict__ dst,
                       const float* __restrict__ bit, int* __restrict__ cursor,
                       const float* __restrict__ a_s, const float* __restrict__ bd,
                       const float* __restrict__ sc, float4* __restrict__ recs, int E) {
    int e = blockIdx.x * blockDim.x + threadIdx.x;
    if (e >= E) return;
    int s = src[e], d = dst[e];
    float bv = bit[e];
    float logit = a_s[s] + sc[0] * bv + bd[d] + sc[1];
    float w = __expf(lrelu(logit, 0.2f));
    int p = atomicAdd(&cursor[d], 1);
    recs[p] = make_float4(__int_as_float(s), w, w * bv, 0.f);
}

// ---------- per-node aggregate -> h_node fp16; 64 thr, 2 ch/thread ----------
__global__ void __launch_bounds__(64, 4) k_node(const float* __restrict__ feat,
                                                const float* __restrict__ Wnm,
                                                const float* __restrict__ b_nm,
                                                const __half* __restrict__ Ah,
                                                const int* __restrict__ row_off,
                                                const float4* __restrict__ recs,
                                                __half* __restrict__ h_node) {
    int v = blockIdx.x;
    int t = threadIdx.x;
    int rs = row_off[v], re = row_off[v + 1];
    h2f* outp = (h2f*)&h_node[(size_t)v * 128 + 2 * t];
    const float4* fr = (const float4*)(feat + (size_t)v * 16);
    float fv[16];
    *(float4*)&fv[0]  = fr[0];
    *(float4*)&fv[4]  = fr[1];
    *(float4*)&fv[8]  = fr[2];
    *(float4*)&fv[12] = fr[3];
    float Bx = 0.f, By = 0.f;
#pragma unroll
    for (int k = 0; k < 16; k++) {
        float2 wr = *(const float2*)&Wnm[(129 + k) * 128 + 2 * t];
        Bx = fmaf(fv[k], wr.x, Bx);
        By = fmaf(fv[k], wr.y, By);
    }
    if (re == rs) { h2f z; z[0] = (_Float16)0.f; z[1] = (_Float16)0.f; *outp = z; return; }
    float ax = 0.f, ay = 0.f, sw = 0.f, swb = 0.f;
#pragma unroll 4
    for (int p = rs; p < re; ++p) {
        float4 rec = recs[p];
        int sv = __float_as_int(rec.x);
        float2 av = __half22float2(*(const __half2*)&Ah[(size_t)sv * 128 + 2 * t]);
        ax = fmaf(rec.y, av.x, ax);
        ay = fmaf(rec.y, av.y, ay);
        sw += rec.y;
        swb += rec.z;
    }
    float inv = 1.f / sw;
    float2 wb = *(const float2*)&Wnm[128 * 128 + 2 * t];
    float2 bn = *(const float2*)&b_nm[2 * t];
    float hx = fmaf(swb * inv, wb.x, ax * inv) + Bx + bn.x;
    float hy = fmaf(swb * inv, wb.y, ay * inv) + By + bn.y;
    h2f o; o[0] = (_Float16)fmaxf(hx, 0.f); o[1] = (_Float16)fmaxf(hy, 0.f);
    *outp = o;
}

// ---------- out = bo2 + sum_c lrelu(h_node@Wo1+bo1,0.1)[c]*Wo2[c], MFMA ----------
__global__ void __launch_bounds__(256) k_out(const __half* __restrict__ h_node,
                                             const float* __restrict__ Wo1,
                                             const float* __restrict__ bo1,
                                             const float* __restrict__ Wo2,
                                             const float* __restrict__ bo2,
                                             float* __restrict__ out,
                                             int n, int ntiles) {
    __shared__ __half Wt[128 * 136];
    int t = threadIdx.x;
    for (int idx = t; idx < 128 * 128; idx += 256) {
        int k = idx >> 7, c = idx & 127;
        Wt[c * 136 + k] = __float2half_rn(Wo1[idx]);
    }
    __syncthreads();
    int wave = t >> 6, lane = t & 63;
    int c = lane & 15, q = lane >> 4;
    float b1v[8], w2v[8];
#pragma unroll
    for (int ct = 0; ct < 8; ct++) {
        b1v[ct] = bo1[ct * 16 + c];
        w2v[ct] = Wo2[ct * 16 + c];
    }
    float bias2 = bo2[0];
    for (int tile = blockIdx.x * 4 + wave; tile < ntiles; tile += gridDim.x * 4) {
        int rowbase = tile * 16;
        int rm = min(rowbase + c, n - 1);
        h8 af[4];
#pragma unroll
        for (int ks = 0; ks < 4; ks++)
            af[ks] = *(const h8*)&h_node[(size_t)rm * 128 + ks * 32 + q * 8];
        f4 acc[8];
#pragma unroll
        for (int ct = 0; ct < 8; ct++) acc[ct] = (f4)(0.f);
#pragma unroll
        for (int ct = 0; ct < 8; ct++) {
#pragma unroll
            for (int ks = 0; ks < 4; ks++) {
                h8 bf = *(const h8*)&Wt[(ct * 16 + c) * 136 + ks * 32 + q * 8];
                acc[ct] = __builtin_amdgcn_mfma_f32_16x16x32_f16(af[ks], bf, acc[ct], 0, 0, 0);
            }
        }
        int rlim = n - rowbase;
        float s0 = 0.f, s1 = 0.f, s2 = 0.f, s3 = 0.f;
#pragma unroll
        for (int ct = 0; ct < 8; ct++) {
            s0 = fmaf(lrelu(acc[ct][0] + b1v[ct], 0.1f), w2v[ct], s0);
            s1 = fmaf(lrelu(acc[ct][1] + b1v[ct], 0.1f), w2v[ct], s1);
            s2 = fmaf(lrelu(acc[ct][2] + b1v[ct], 0.1f), w2v[ct], s2);
            s3 = fmaf(lrelu(acc[ct][3] + b1v[ct], 0.1f), w2v[ct], s3);
        }
#pragma unroll
        for (int off = 1; off < 16; off <<= 1) {
            s0 += __shfl_xor(s0, off, 64);
            s1 += __shfl_xor(s1, off, 64);
            s2 += __shfl_xor(s2, off, 64);
            s3 += __shfl_xor(s3, off, 64);
        }
        if (c == 0) {
            if (q * 4 + 0 < rlim) out[rowbase + q * 4 + 0] = bias2 + s0;
            if (q * 4 + 1 < rlim) out[rowbase + q * 4 + 1] = bias2 + s1;
            if (q * 4 + 2 < rlim) out[rowbase + q * 4 + 2] = bias2 + s2;
            if (q * 4 + 3 < rlim) out[rowbase + q * 4 + 3] = bias2 + s3;
        }
    }
}

extern "C" void kernel_launch(void* const* d_in, const int* in_sizes, int n_in,
                              void* d_out, int out_size, void* d_ws, size_t ws_size,
                              hipStream_t stream) {
    const float* feat = (const float*)d_in[0];
    const float* bit  = (const float*)d_in[1];
    const int*   src  = (const int*)d_in[2];
    const int*   dst  = (const int*)d_in[3];
    const float* W1   = (const float*)d_in[4];
    const float* b1   = (const float*)d_in[5];
    const float* W2   = (const float*)d_in[6];
    const float* b2   = (const float*)d_in[7];
    const float* Wnm  = (const float*)d_in[8];
    const float* bnm  = (const float*)d_in[9];
    const float* attn = (const float*)d_in[10];
    const float* Wo1  = (const float*)d_in[11];
    const float* bo1  = (const float*)d_in[12];
    const float* Wo2  = (const float*)d_in[13];
    const float* bo2  = (const float*)d_in[14];
    float* out = (float*)d_out;
    int n = in_sizes[0] / 16;
    int E = in_sizes[2];
    int ntiles = (n + 15) / 16;

    char* wsp = (char*)d_ws;
    size_t off = 0;
    auto alloc = [&](size_t bytes) -> void* {
        void* p = wsp + off;
        off = (off + bytes + 255) & ~(size_t)255;
        return p;
    };
    __half* Ah       = (__half*)alloc((size_t)n * 128 * 2);
    __half* hH       = (__half*)alloc((size_t)n * 128 * 2);   // h, then h_node
    __half* t1h      = (__half*)alloc((size_t)n * 64 * 2);
    float*  a_s      = (float*)alloc((size_t)n * 4);
    float*  bd       = (float*)alloc((size_t)n * 4);
    int*    counts   = (int*)alloc((size_t)n * 4);
    int*    row_off  = (int*)alloc((size_t)(n + 1) * 4);
    int*    cursor   = (int*)alloc((size_t)n * 4);
    int*    partials = (int*)alloc(8192);
    float*  sc       = (float*)alloc(256);
    float4* recs     = (float4*)alloc((size_t)E * 16);

    int nb256 = (n + 255) / 256;
    int eb256 = (E + 255) / 256;
    int nscan = (n + 1023) / 1024;

    k_init<<<nb256, 256, 0, stream>>>(counts, n);
    k_hist<<<eb256, 256, 0, stream>>>(dst, counts, E);
    k_scan_a<<<nscan, 256, 0, stream>>>(counts, row_off, partials, n);
    k_scan_b<<<1, 64, 0, stream>>>(partials, nscan);
    k_scan_c<<<nb256, 256, 0, stream>>>(row_off, partials, cursor, n, E);
    k_scalars<<<1, 128, 0, stream>>>(Wnm, bnm, attn, sc);
    k_bd<<<nb256, 256, 0, stream>>>(feat, sc, bd, n);
    k_t1<<<2048, 256, 0, stream>>>(feat, W1, b1, t1h, n);
    k_h<<<1024, 256, 0, stream>>>(t1h, W2, b2, hH, n, ntiles);
    k_A<<<1024, 256, 0, stream>>>(hH, Wnm, attn, Ah, a_s, n, ntiles);
    k_fill<<<eb256, 256, 0, stream>>>(src, dst, bit, cursor, a_s, bd, sc, recs, E);
    k_node<<<n, 64, 0, stream>>>(feat, Wnm, bnm, Ah, row_off, recs, hH);
    k_out<<<1024, 256, 0, stream>>>(hH, Wo1, bo1, Wo2, bo2, out, n, ntiles);
}